// Round 26
// baseline (82.547 us; speedup 1.0000x reference)
//
#include <hip/hip_runtime.h>
#include <hip/hip_bf16.h>
#include <math.h>

#define IN_DIM 128
#define C_DIM 64
#define BKT_CHUNK 8192
#define BS 64            // nodes per bucket
#define SA_CAP 1440      // LDS record capacity per bucket (~ +10 sigma)

typedef short bf16x8 __attribute__((ext_vector_type(8)));
typedef float f32x4 __attribute__((ext_vector_type(4)));

static __device__ __forceinline__ unsigned short f2bf(float f) {
    unsigned int u = __float_as_uint(f);
    u += 0x7FFFu + ((u >> 16) & 1u);          // round-to-nearest-even
    return (unsigned short)(u >> 16);
}
static __device__ __forceinline__ float bf2f(unsigned short h) {
    return __uint_as_float(((unsigned int)h) << 16);
}

// LDS overlay for K1: GEMM blocks use WT (16KB); bucket blocks use counters
// (12KB). Union keeps LDS at 16KB -> ~10 blocks/CU (R21's 45KB was the bug).
// aligned(16) IS LOAD-BEARING (R17: without it WT reads become ds_read_u16).
struct SG { unsigned short WT[64][128]; };                         // 16384 B
struct SB { int cnt[1024]; int run[1024]; int cur[1024]; };        // 12288 B
union __attribute__((aligned(16))) SU { SG g; SB b; };

// ---------------------------------------------------------------------------
// FUSED kernel 1: blockIdx < GB  -> GEMM, 128 rows/block (two 64-row halves,
//   single-term bf16(x)·bf16(W));
//                 blockIdx >= GB -> bucket-partition (64 nodes/bucket,
//   chunk=8192 so per-chunk-per-bucket runs ~10 recs -> line-merge OK, R21).
// ---------------------------------------------------------------------------
__global__ __launch_bounds__(256) void k_gemm_bucket(
    const float* __restrict__ x, const float* __restrict__ W,
    const float* __restrict__ corrs,
    const float* __restrict__ att_i, const float* __restrict__ att_j,
    const float* __restrict__ att_em_i, const float* __restrict__ att_em_j,
    unsigned short* __restrict__ g_bf, float* __restrict__ s_i, float* __restrict__ s_j,
    int N, int GB,
    const int* __restrict__ src, const int* __restrict__ dst,
    int E, int NB, int CAP,
    int* __restrict__ bucket_cnt, unsigned int* __restrict__ staging)
{
    __shared__ SU sm;
    int tid = threadIdx.x;

    if (blockIdx.x >= GB) {
        // ---------------- bucket part ----------------
        for (int i = tid; i < NB; i += 256) sm.b.cnt[i] = 0;
        __syncthreads();

        int T = E + N;
        int base = (blockIdx.x - GB) * BKT_CHUNK;
#pragma unroll 8
        for (int k = 0; k < BKT_CHUNK / 256; ++k) {
            int i = base + k * 256 + tid;
            if (i < T) {
                int d = (i < E) ? dst[i] : (i - E);
                atomicAdd(&sm.b.cnt[d >> 6], 1);
            }
        }
        __syncthreads();
        for (int i = tid; i < NB; i += 256) {
            sm.b.cur[i] = 0;
            if (sm.b.cnt[i] > 0)
                sm.b.run[i] = atomicAdd(&bucket_cnt[i], sm.b.cnt[i]);
        }
        __syncthreads();
#pragma unroll 8
        for (int k = 0; k < BKT_CHUNK / 256; ++k) {
            int i = base + k * 256 + tid;
            if (i < T) {
                int d, s;
                if (i < E) { d = dst[i]; s = src[i]; }
                else       { d = i - E; s = d; }      // self loop
                int b = d >> 6;
                int ofs = atomicAdd(&sm.b.cur[b], 1);
                int pos = sm.b.run[b] + ofs;
                if (pos < CAP)
                    staging[(size_t)b * CAP + pos] =
                        (unsigned)s | ((unsigned)(d & 63) << 16);
            }
        }
        return;
    }

    // ---------------- GEMM part (128 rows per block, 2 halves) -------------
#pragma unroll
    for (int p = 0; p < 8; ++p) {
        int f = p * 1024 + tid * 4;               // flat into W[128][64]
        f32x4 w4 = *(const f32x4*)(W + f);
        int k  = f >> 6;
        int c0 = f & 63;
#pragma unroll
        for (int i = 0; i < 4; ++i) {
            int c = c0 + i;
            int ks = k ^ ((c & 7) << 3);
            sm.g.WT[c][ks] = f2bf(w4[i]);
        }
    }
    __syncthreads();

    int wv = tid >> 6, lane = tid & 63;
    int mrow = lane & 15;
    int kgrp = lane >> 4;

    float ai[4], aj[4], aei[4], aej[4];
#pragma unroll
    for (int t = 0; t < 4; ++t) {
        ai[t]  = att_i[t * 16 + mrow];
        aj[t]  = att_j[t * 16 + mrow];
        aei[t] = att_em_i[t * 16 + mrow];
        aej[t] = att_em_j[t * 16 + mrow];
    }

    for (int half = 0; half < 2; ++half) {
        int row = blockIdx.x * 128 + half * 64 + wv * 16 + mrow;
        int rowc = min(row, N - 1);

        f32x4 acc[4];
#pragma unroll
        for (int t = 0; t < 4; ++t) { f32x4 z = {0.f, 0.f, 0.f, 0.f}; acc[t] = z; }

        f32x4 xa[4], xb[4];
#pragma unroll
        for (int s = 0; s < 4; ++s) {
            const float* xp = x + (size_t)rowc * IN_DIM + s * 32 + kgrp * 8;
            xa[s] = *(const f32x4*)xp;
            xb[s] = *(const f32x4*)(xp + 4);
        }

#pragma unroll
        for (int s = 0; s < 4; ++s) {
            bf16x8 ah;
#pragma unroll
            for (int i = 0; i < 4; ++i) {
                ah[i]     = (short)f2bf(xa[s][i]);
                ah[4 + i] = (short)f2bf(xb[s][i]);
            }
            int kbase = s * 32 + kgrp * 8;
#pragma unroll
            for (int t = 0; t < 4; ++t) {
                int c  = t * 16 + mrow;
                int ks = kbase ^ ((c & 7) << 3);
                bf16x8 bh = *(const bf16x8*)&sm.g.WT[c][ks];
                acc[t] = __builtin_amdgcn_mfma_f32_16x16x32_bf16(ah, bh, acc[t], 0, 0, 0);
            }
        }

        int crow_base = blockIdx.x * 128 + half * 64 + wv * 16 + (lane >> 4) * 4;
#pragma unroll
        for (int r = 0; r < 4; ++r) {
            int grow  = crow_base + r;
            int growc = min(grow, N - 1);
            float vi = 0.f, vj = 0.f;
            ushort4 hv;
#pragma unroll
            for (int t = 0; t < 4; ++t) {
                float gv = acc[t][r];
                float cv = corrs[(size_t)growc * 64 + t * 16 + mrow];
                unsigned short h = f2bf(gv);
                if (t == 0) hv.x = h; else if (t == 1) hv.y = h;
                else if (t == 2) hv.z = h; else hv.w = h;
                vi = fmaf(gv, ai[t], fmaf(cv, aei[t], vi));
                vj = fmaf(gv, aj[t], fmaf(cv, aej[t], vj));
            }
            if (grow < N)
                *(ushort4*)(g_bf + (size_t)grow * C_DIM + mrow * 4) = hv;
#pragma unroll
            for (int o = 1; o < 16; o <<= 1) {
                vi += __shfl_xor(vi, o);
                vj += __shfl_xor(vj, o);
            }
            if (mrow == 0 && grow < N) { s_i[grow] = vi; s_j[grow] = vj; }
        }
    }
}

// ---------------------------------------------------------------------------
// FUSED kernel 2: per-64-bucket scatter + aggregate (records stay in LDS).
// Phase A: one coalesced read of own bucket's staging -> LDS raw; count 64
//   local nodes; wave-0 64-wide scan; place into wrecs with PRECOMPUTED
//   bf16 weight (exp(leaky(si+sj))).
// Phase B: wave per node (16/wave), 8 edges x 8 lanes, records from LDS,
//   16B g_bf gathers, max-free softmax, bias + ReLU.
// REQUIRES N <= 65536 (src in 16 bits).
// ---------------------------------------------------------------------------
__global__ __launch_bounds__(256) void k_scatter_agg(
    const unsigned int* __restrict__ staging, const int* __restrict__ bucket_cnt,
    int N, int CAP,
    const float* __restrict__ s_i, const float* __restrict__ s_j,
    const unsigned short* __restrict__ g_bf,
    const float* __restrict__ bias, float* __restrict__ out)
{
    __shared__ unsigned int raw[SA_CAP];
    __shared__ unsigned int wrecs[SA_CAP];
    __shared__ int   cnt[BS];
    __shared__ int   off[BS + 1];
    __shared__ int   cur[BS];
    __shared__ float si_l[BS];

    int b = blockIdx.x, tid = threadIdx.x;
    int lo = b * BS;
    int bcnt = min(bucket_cnt[b], CAP);
    const unsigned int* sb = staging + (size_t)b * CAP;

    // ---- phase A ----
    for (int r = tid; r < bcnt; r += 256) raw[r] = sb[r];
    if (tid < BS) {
        cnt[tid] = 0;
        si_l[tid] = (lo + tid < N) ? s_i[lo + tid] : 0.f;
    }
    __syncthreads();

    for (int r = tid; r < bcnt; r += 256)
        atomicAdd(&cnt[(raw[r] >> 16) & 63], 1);
    __syncthreads();

    if (tid < 64) {                         // wave 0: 64-wide inclusive scan
        int s = cnt[tid];
        int incl = s;
#pragma unroll
        for (int o = 1; o < 64; o <<= 1) {
            int u = __shfl_up(incl, o);
            if (tid >= o) incl += u;
        }
        off[tid] = incl - s;
        cur[tid] = incl - s;
        if (tid == 63) off[64] = incl;
    }
    __syncthreads();

    for (int r = tid; r < bcnt; r += 256) {
        unsigned int rec = raw[r];
        int dl   = (rec >> 16) & 63;
        int srcn = rec & 0xFFFFu;
        float a = si_l[dl] + s_j[srcn];
        a = (a > 0.f) ? a : 0.2f * a;
        float w = __expf(a);
        int slot = atomicAdd(&cur[dl], 1);
        if (slot < SA_CAP)
            wrecs[slot] = ((unsigned)f2bf(w) << 16) | (unsigned)srcn;
    }
    __syncthreads();

    // ---- phase B: aggregate 64 nodes, 16 per wave ----
    int wave = tid >> 6, lane = tid & 63;
    int grp = lane >> 3;          // edge slot 0..7
    int cl  = lane & 7;           // owns permuted slots cl*8 .. cl*8+7
    for (int nl = wave; nl < BS; nl += 4) {
        int n = lo + nl;
        if (n >= N) break;
        int start = off[nl];
        int end   = min(off[nl + 1], SA_CAP);

        float a0 = 0.f, a1 = 0.f, a2 = 0.f, a3 = 0.f;
        float a4 = 0.f, a5 = 0.f, a6 = 0.f, a7 = 0.f, den = 0.f;
#pragma unroll 2
        for (int e0 = start; e0 < end; e0 += 8) {
            int e = e0 + grp;
            if (e < end) {
                unsigned int rec = wrecs[e];
                int   srcn = rec & 0xFFFFu;
                float w    = bf2f((unsigned short)(rec >> 16));
                const ushort4* gp = (const ushort4*)(g_bf + (size_t)srcn * C_DIM + (cl << 3));
                ushort4 g0 = gp[0];
                ushort4 g1 = gp[1];
                a0 = fmaf(w, bf2f(g0.x), a0);
                a1 = fmaf(w, bf2f(g0.y), a1);
                a2 = fmaf(w, bf2f(g0.z), a2);
                a3 = fmaf(w, bf2f(g0.w), a3);
                a4 = fmaf(w, bf2f(g1.x), a4);
                a5 = fmaf(w, bf2f(g1.y), a5);
                a6 = fmaf(w, bf2f(g1.z), a6);
                a7 = fmaf(w, bf2f(g1.w), a7);
                den += w;
            }
        }
#pragma unroll
        for (int o = 8; o < 64; o <<= 1) {
            a0  += __shfl_xor(a0, o);
            a1  += __shfl_xor(a1, o);
            a2  += __shfl_xor(a2, o);
            a3  += __shfl_xor(a3, o);
            a4  += __shfl_xor(a4, o);
            a5  += __shfl_xor(a5, o);
            a6  += __shfl_xor(a6, o);
            a7  += __shfl_xor(a7, o);
            den += __shfl_xor(den, o);
        }
        if (grp == 0) {
            float inv = 1.f / (den + 1e-16f);
            float av[8] = {a0, a1, a2, a3, a4, a5, a6, a7};
            float* op = out + (size_t)n * C_DIM;
#pragma unroll
            for (int j = 0; j < 8; ++j) {
                int p  = (cl << 3) + j;                 // permuted slot
                int ch = ((p & 3) << 4) + (p >> 2);     // real channel
                op[ch] = fmaxf(fmaf(av[j], inv, bias[ch]), 0.f);
            }
        }
    }
}

// ---------------------------------------------------------------------------
extern "C" void kernel_launch(void* const* d_in, const int* in_sizes, int n_in,
                              void* d_out, int out_size, void* d_ws, size_t ws_size,
                              hipStream_t stream)
{
    const float* x        = (const float*)d_in[0];
    const int*   eidx     = (const int*)  d_in[1];
    const float* corrs    = (const float*)d_in[2];
    const float* W        = (const float*)d_in[3];
    const float* att_i    = (const float*)d_in[4];
    const float* att_j    = (const float*)d_in[5];
    const float* att_em_i = (const float*)d_in[6];
    const float* att_em_j = (const float*)d_in[7];
    const float* bias     = (const float*)d_in[8];
    float* out = (float*)d_out;

    int N = in_sizes[0] / IN_DIM;
    int E = in_sizes[1] / 2;
    const int* src = eidx;
    const int* dst = eidx + E;

    int T  = E + N;
    int NB = (N + BS - 1) / BS;                    // 64 nodes per bucket
    int CAP = ((T + NB - 1) / NB);
    CAP = CAP + CAP / 4;                           // +25% (~+8 sigma)
    CAP = (CAP + 63) & ~63;
    if (CAP > SA_CAP) CAP = SA_CAP;

    char* ws = (char*)d_ws;
    size_t off = 0;
    auto alloc = [&](size_t bytes) -> void* {
        void* p = ws + off;
        off += (bytes + 255) & ~(size_t)255;
        return p;
    };
    unsigned short* g_bf = (unsigned short*)alloc((size_t)N * C_DIM * sizeof(unsigned short));
    float* s_i       = (float*)alloc((size_t)N * sizeof(float));
    float* s_j       = (float*)alloc((size_t)N * sizeof(float));
    unsigned int* staging = (unsigned int*)alloc((size_t)NB * CAP * sizeof(unsigned int));
    int*   bucket_cnt= (int*)alloc((size_t)1024 * sizeof(int));
    (void)ws_size; (void)n_in; (void)out_size;

    hipMemsetAsync(bucket_cnt, 0, 1024 * sizeof(int), stream);

    int GB = (N + 127) / 128;                      // gemm blocks (128 rows each)
    int BB = (T + BKT_CHUNK - 1) / BKT_CHUNK;      // bucket blocks
    k_gemm_bucket<<<GB + BB, 256, 0, stream>>>(
        x, W, corrs, att_i, att_j, att_em_i, att_em_j, g_bf, s_i, s_j,
        N, GB, src, dst, E, NB, CAP, bucket_cnt, staging);

    k_scatter_agg<<<NB, 256, 0, stream>>>(
        staging, bucket_cnt, N, CAP, s_i, s_j, g_bf, bias, out);
}

// Round 27
// 73.059 us; speedup vs baseline: 1.1299x; 1.1299x over previous
//
#include <hip/hip_runtime.h>
#include <hip/hip_bf16.h>
#include <math.h>

#define IN_DIM 128
#define C_DIM 64
#define BKT_CHUNK 4096
#define AGG_LDS_RECS 1280

typedef short bf16x8 __attribute__((ext_vector_type(8)));
typedef float f32x4 __attribute__((ext_vector_type(4)));

static __device__ __forceinline__ unsigned short f2bf(float f) {
    unsigned int u = __float_as_uint(f);
    u += 0x7FFFu + ((u >> 16) & 1u);          // round-to-nearest-even
    return (unsigned short)(u >> 16);
}
static __device__ __forceinline__ float bf2f(unsigned short h) {
    return __uint_as_float(((unsigned int)h) << 16);
}

// ---------------------------------------------------------------------------
// FUSED kernel 1 (champion, R25): blockIdx < GB -> GEMM, 128 rows/block
// (two 64-row halves, single-term bf16(x)·bf16(W));
// blockIdx >= GB -> bucket-partition (256 nodes/bucket).
// ---------------------------------------------------------------------------
__global__ __launch_bounds__(256) void k_gemm_bucket(
    const float* __restrict__ x, const float* __restrict__ W,
    const float* __restrict__ corrs,
    const float* __restrict__ att_i, const float* __restrict__ att_j,
    const float* __restrict__ att_em_i, const float* __restrict__ att_em_j,
    unsigned short* __restrict__ g_bf, float* __restrict__ s_i, float* __restrict__ s_j,
    int N, int GB,
    const int* __restrict__ src, const int* __restrict__ dst,
    int E, int NB, int CAP,
    int* __restrict__ bucket_cnt, unsigned int* __restrict__ staging)
{
    __shared__ __attribute__((aligned(16))) unsigned short WT[64][128]; // 16KB
    __shared__ int cnt[256];
    __shared__ int run[256];
    __shared__ int cur[256];

    int tid = threadIdx.x;

    if (blockIdx.x >= GB) {
        // ---------------- bucket part ----------------
        cnt[tid] = 0;
        __syncthreads();

        int T = E + N;
        int base = (blockIdx.x - GB) * BKT_CHUNK;
#pragma unroll
        for (int k = 0; k < BKT_CHUNK / 256; ++k) {
            int i = base + k * 256 + tid;
            if (i < T) {
                int d = (i < E) ? dst[i] : (i - E);
                atomicAdd(&cnt[d >> 8], 1);
            }
        }
        __syncthreads();
        if (tid < NB && cnt[tid] > 0) run[tid] = atomicAdd(&bucket_cnt[tid], cnt[tid]);
        cur[tid] = 0;
        __syncthreads();
#pragma unroll
        for (int k = 0; k < BKT_CHUNK / 256; ++k) {
            int i = base + k * 256 + tid;
            if (i < T) {
                int d, s;
                if (i < E) { d = dst[i]; s = src[i]; }
                else       { d = i - E; s = d; }      // self loop
                int b = d >> 8;
                int ofs = atomicAdd(&cur[b], 1);
                int pos = run[b] + ofs;
                if (pos < CAP)
                    staging[(size_t)b * CAP + pos] =
                        (unsigned)s | ((unsigned)(d & 255) << 16);
            }
        }
        return;
    }

    // ---------------- GEMM part (128 rows per block, 2 halves) -------------
#pragma unroll
    for (int p = 0; p < 8; ++p) {
        int f = p * 1024 + tid * 4;               // flat into W[128][64]
        f32x4 w4 = *(const f32x4*)(W + f);
        int k  = f >> 6;
        int c0 = f & 63;
#pragma unroll
        for (int i = 0; i < 4; ++i) {
            int c = c0 + i;
            int ks = k ^ ((c & 7) << 3);
            WT[c][ks] = f2bf(w4[i]);
        }
    }
    __syncthreads();

    int wv = tid >> 6, lane = tid & 63;
    int mrow = lane & 15;
    int kgrp = lane >> 4;

    float ai[4], aj[4], aei[4], aej[4];
#pragma unroll
    for (int t = 0; t < 4; ++t) {
        ai[t]  = att_i[t * 16 + mrow];
        aj[t]  = att_j[t * 16 + mrow];
        aei[t] = att_em_i[t * 16 + mrow];
        aej[t] = att_em_j[t * 16 + mrow];
    }

    for (int half = 0; half < 2; ++half) {
        int row = blockIdx.x * 128 + half * 64 + wv * 16 + mrow;
        int rowc = min(row, N - 1);

        f32x4 acc[4];
#pragma unroll
        for (int t = 0; t < 4; ++t) { f32x4 z = {0.f, 0.f, 0.f, 0.f}; acc[t] = z; }

        f32x4 xa[4], xb[4];
#pragma unroll
        for (int s = 0; s < 4; ++s) {
            const float* xp = x + (size_t)rowc * IN_DIM + s * 32 + kgrp * 8;
            xa[s] = *(const f32x4*)xp;
            xb[s] = *(const f32x4*)(xp + 4);
        }

#pragma unroll
        for (int s = 0; s < 4; ++s) {
            bf16x8 ah;
#pragma unroll
            for (int i = 0; i < 4; ++i) {
                ah[i]     = (short)f2bf(xa[s][i]);
                ah[4 + i] = (short)f2bf(xb[s][i]);
            }
            int kbase = s * 32 + kgrp * 8;
#pragma unroll
            for (int t = 0; t < 4; ++t) {
                int c  = t * 16 + mrow;
                int ks = kbase ^ ((c & 7) << 3);
                bf16x8 bh = *(const bf16x8*)&WT[c][ks];
                acc[t] = __builtin_amdgcn_mfma_f32_16x16x32_bf16(ah, bh, acc[t], 0, 0, 0);
            }
        }

        int crow_base = blockIdx.x * 128 + half * 64 + wv * 16 + (lane >> 4) * 4;
#pragma unroll
        for (int r = 0; r < 4; ++r) {
            int grow  = crow_base + r;
            int growc = min(grow, N - 1);
            float vi = 0.f, vj = 0.f;
            ushort4 hv;
#pragma unroll
            for (int t = 0; t < 4; ++t) {
                float gv = acc[t][r];
                float cv = corrs[(size_t)growc * 64 + t * 16 + mrow];
                unsigned short h = f2bf(gv);
                if (t == 0) hv.x = h; else if (t == 1) hv.y = h;
                else if (t == 2) hv.z = h; else hv.w = h;
                vi = fmaf(gv, ai[t], fmaf(cv, aei[t], vi));
                vj = fmaf(gv, aj[t], fmaf(cv, aej[t], vj));
            }
            if (grow < N)
                *(ushort4*)(g_bf + (size_t)grow * C_DIM + mrow * 4) = hv;
#pragma unroll
            for (int o = 1; o < 16; o <<= 1) {
                vi += __shfl_xor(vi, o);
                vj += __shfl_xor(vj, o);
            }
            if (mrow == 0 && grow < N) { s_i[grow] = vi; s_j[grow] = vj; }
        }
    }
}

// ---------------------------------------------------------------------------
// Phase 2: one block per bucket (256 nodes). LDS count -> scan ->
// row_start/row_end -> scatter records with PRECOMPUTED bf16 weight:
// rec = (bf16(w)<<16)|src, w = exp(leaky(s_i[d]+s_j[s])).
// REQUIRES N <= 65536 (src in 16 bits).
// ---------------------------------------------------------------------------
__global__ __launch_bounds__(256) void k_scatter(
    const unsigned int* __restrict__ staging, const int* __restrict__ bucket_cnt,
    int N, int CAP,
    const float* __restrict__ s_i, const float* __restrict__ s_j,
    int* __restrict__ row_start, int* __restrict__ row_end,
    unsigned int* __restrict__ edge_rec)
{
    __shared__ int cnt[256];
    __shared__ int off[257];
    __shared__ int cur[256];
    __shared__ int wsum[4];
    __shared__ float si_l[256];

    int b = blockIdx.x, t = threadIdx.x;
    int lo = b << 8;
    int hi = min(lo + 256, N);
    int bcnt = min(bucket_cnt[b], CAP);
    const unsigned int* sb = staging + (size_t)b * CAP;

    cnt[t] = 0;
    if (lo + t < N) si_l[t] = s_i[lo + t];
    __syncthreads();

    for (int r = t; r < bcnt; r += 256)
        atomicAdd(&cnt[(sb[r] >> 16) & 255], 1);
    __syncthreads();

    int s = cnt[t];
    int lane = t & 63, wv = t >> 6;
    int incl = s;
#pragma unroll
    for (int o = 1; o < 64; o <<= 1) {
        int u = __shfl_up(incl, o);
        if (lane >= o) incl += u;
    }
    if (lane == 63) wsum[wv] = incl;
    __syncthreads();
    int woff = 0;
    for (int w = 0; w < wv; ++w) woff += wsum[w];
    int ex = woff + incl - s;
    off[t] = ex;
    cur[t] = ex;
    if (t == 255) off[256] = woff + incl;
    __syncthreads();

    int rawb = b * CAP;
    for (int i = t; i < hi - lo; i += 256) {
        row_start[lo + i] = rawb + off[i];
        row_end[lo + i]   = rawb + off[i + 1];
    }
    for (int r = t; r < bcnt; r += 256) {
        unsigned int rec = sb[r];
        int dl   = (rec >> 16) & 255;
        int srcn = rec & 0xFFFFu;
        float a = si_l[dl] + s_j[srcn];
        a = (a > 0.f) ? a : 0.2f * a;
        float w = __expf(a);
        int slot = atomicAdd(&cur[dl], 1);
        edge_rec[rawb + slot] = ((unsigned)f2bf(w) << 16) | (unsigned)srcn;
    }
}

// ---------------------------------------------------------------------------
// Fused single-pass softmax-aggregate (champion). One wave per node;
// max-free softmax. Block's 4 nodes own one contiguous record range;
// coalesced-preload it to LDS. 8 edges x 8 lanes; lane owns 8 permuted
// channel slots (2 x ushort4).
// ---------------------------------------------------------------------------
__global__ __launch_bounds__(256) void k_aggregate(
    const unsigned short* __restrict__ g_bf,
    const int* __restrict__ row_start, const int* __restrict__ row_end,
    const unsigned int* __restrict__ edge_rec,
    const float* __restrict__ bias, float* __restrict__ out, int N)
{
    __shared__ unsigned int recs[AGG_LDS_RECS];

    int tid  = threadIdx.x;
    int n0 = blockIdx.x * 4;
    if (n0 >= N) return;
    int nlast = min(n0 + 3, N - 1);

    int s0 = row_start[n0];
    int e3 = row_end[nlast];
    int rc = e3 - s0;
    bool lds_ok = (rc <= AGG_LDS_RECS);
    if (lds_ok) {
        for (int i = tid; i < rc; i += 256)
            recs[i] = edge_rec[s0 + i];
    }
    __syncthreads();

    int wave = tid >> 6, lane = tid & 63;
    int n = n0 + wave;
    if (n >= N) return;

    int start = row_start[n];
    int end   = row_end[n];

    int grp = lane >> 3;          // edge slot 0..7
    int cl  = lane & 7;           // owns permuted slots cl*8 .. cl*8+7
    float a0 = 0.f, a1 = 0.f, a2 = 0.f, a3 = 0.f;
    float a4 = 0.f, a5 = 0.f, a6 = 0.f, a7 = 0.f, den = 0.f;
#pragma unroll 2
    for (int e0 = start; e0 < end; e0 += 8) {
        int e = e0 + grp;
        if (e < end) {
            unsigned int rec = lds_ok ? recs[e - s0] : edge_rec[e];
            int   srcn = rec & 0xFFFFu;
            float w    = bf2f((unsigned short)(rec >> 16));
            const ushort4* gp = (const ushort4*)(g_bf + (size_t)srcn * C_DIM + (cl << 3));
            ushort4 g0 = gp[0];
            ushort4 g1 = gp[1];
            a0 = fmaf(w, bf2f(g0.x), a0);
            a1 = fmaf(w, bf2f(g0.y), a1);
            a2 = fmaf(w, bf2f(g0.z), a2);
            a3 = fmaf(w, bf2f(g0.w), a3);
            a4 = fmaf(w, bf2f(g1.x), a4);
            a5 = fmaf(w, bf2f(g1.y), a5);
            a6 = fmaf(w, bf2f(g1.z), a6);
            a7 = fmaf(w, bf2f(g1.w), a7);
            den += w;
        }
    }
#pragma unroll
    for (int o = 8; o < 64; o <<= 1) {
        a0  += __shfl_xor(a0, o);
        a1  += __shfl_xor(a1, o);
        a2  += __shfl_xor(a2, o);
        a3  += __shfl_xor(a3, o);
        a4  += __shfl_xor(a4, o);
        a5  += __shfl_xor(a5, o);
        a6  += __shfl_xor(a6, o);
        a7  += __shfl_xor(a7, o);
        den += __shfl_xor(den, o);
    }
    if (grp == 0) {
        float inv = 1.f / (den + 1e-16f);
        float av[8] = {a0, a1, a2, a3, a4, a5, a6, a7};
        float* op = out + (size_t)n * C_DIM;
#pragma unroll
        for (int j = 0; j < 8; ++j) {
            int p  = (cl << 3) + j;                 // permuted slot
            int ch = ((p & 3) << 4) + (p >> 2);     // real channel
            op[ch] = fmaxf(fmaf(av[j], inv, bias[ch]), 0.f);
        }
    }
}

// ---------------------------------------------------------------------------
extern "C" void kernel_launch(void* const* d_in, const int* in_sizes, int n_in,
                              void* d_out, int out_size, void* d_ws, size_t ws_size,
                              hipStream_t stream)
{
    const float* x        = (const float*)d_in[0];
    const int*   eidx     = (const int*)  d_in[1];
    const float* corrs    = (const float*)d_in[2];
    const float* W        = (const float*)d_in[3];
    const float* att_i    = (const float*)d_in[4];
    const float* att_j    = (const float*)d_in[5];
    const float* att_em_i = (const float*)d_in[6];
    const float* att_em_j = (const float*)d_in[7];
    const float* bias     = (const float*)d_in[8];
    float* out = (float*)d_out;

    int N = in_sizes[0] / IN_DIM;
    int E = in_sizes[1] / 2;
    const int* src = eidx;
    const int* dst = eidx + E;

    int T  = E + N;
    int NB = (N + 255) >> 8;                       // 256 nodes per bucket
    int CAP = ((T + NB - 1) / NB);
    CAP = CAP + CAP / 4;                           // 1.25x slack
    CAP = (CAP + 63) & ~63;

    char* ws = (char*)d_ws;
    size_t off = 0;
    auto alloc = [&](size_t bytes) -> void* {
        void* p = ws + off;
        off += (bytes + 255) & ~(size_t)255;
        return p;
    };
    unsigned short* g_bf = (unsigned short*)alloc((size_t)N * C_DIM * sizeof(unsigned short));
    float* s_i       = (float*)alloc((size_t)N * sizeof(float));
    float* s_j       = (float*)alloc((size_t)N * sizeof(float));
    unsigned int* staging  = (unsigned int*)alloc((size_t)NB * CAP * sizeof(unsigned int));
    unsigned int* edge_rec = (unsigned int*)alloc((size_t)NB * CAP * sizeof(unsigned int));
    int*   row_start = (int*)alloc((size_t)N * sizeof(int));
    int*   row_end   = (int*)alloc((size_t)N * sizeof(int));
    int*   bucket_cnt= (int*)alloc(256 * sizeof(int));
    (void)ws_size; (void)n_in; (void)out_size;

    hipMemsetAsync(bucket_cnt, 0, 256 * sizeof(int), stream);

    int GB = (N + 127) / 128;                      // gemm blocks (128 rows each)
    int BB = (T + BKT_CHUNK - 1) / BKT_CHUNK;      // bucket blocks
    k_gemm_bucket<<<GB + BB, 256, 0, stream>>>(
        x, W, corrs, att_i, att_j, att_em_i, att_em_j, g_bf, s_i, s_j,
        N, GB, src, dst, E, NB, CAP, bucket_cnt, staging);

    k_scatter<<<NB, 256, 0, stream>>>(
        staging, bucket_cnt, N, CAP, s_i, s_j, row_start, row_end, edge_rec);

    k_aggregate<<<(N + 3) / 4, 256, 0, stream>>>(
        g_bf, row_start, row_end, edge_rec, bias, out, N);
}